// Round 2
// baseline (406.363 us; speedup 1.0000x reference)
//
#include <hip/hip_runtime.h>
#include <hip/hip_bf16.h>

constexpr int NR = 12288;   // nodes
constexpr int KF = 256;     // in features
constexpr int DF = 128;     // out features
#define NEGBIG (-1e30f)

typedef __attribute__((ext_vector_type(8))) __bf16 bf16x8;
typedef __attribute__((ext_vector_type(4))) float  f32x4;

__device__ __forceinline__ unsigned short f2bf(float f) {
    union { float f; unsigned u; } v; v.f = f;
    unsigned r = v.u + 0x7FFFu + ((v.u >> 16) & 1u);
    return (unsigned short)(r >> 16);
}

// ---------- Kernel A: h = x@W (fp32 regs), emit hbT (bf16, transposed) + s1/s2
// grid 192 x 256 thr; block tile 64 rows x 128 cols; K-tiles of 64.
__global__ __launch_bounds__(256) void k_gemm_h(
    const float* __restrict__ x, const float* __restrict__ W,
    const float* __restrict__ a1, const float* __restrict__ a2,
    unsigned short* __restrict__ hbT, float* __restrict__ s1, float* __restrict__ s2)
{
    __shared__ __align__(16) float xs[64][65];
    __shared__ __align__(16) float ws[64][132];
    const int t  = threadIdx.x;
    const int tx = t & 15, ty = t >> 4;
    const int rowbase = blockIdx.x * 64;

    float acc[4][8];
#pragma unroll
    for (int i = 0; i < 4; ++i)
#pragma unroll
        for (int j = 0; j < 8; ++j) acc[i][j] = 0.f;

    for (int kt = 0; kt < KF; kt += 64) {
        {   // stage x tile [64][64]
            int row = t >> 2, k0 = (t & 3) * 16;
            const float4* src = (const float4*)(x + (size_t)(rowbase + row) * KF + kt + k0);
            float4 v0 = src[0], v1 = src[1], v2 = src[2], v3 = src[3];
            xs[row][k0+ 0]=v0.x; xs[row][k0+ 1]=v0.y; xs[row][k0+ 2]=v0.z; xs[row][k0+ 3]=v0.w;
            xs[row][k0+ 4]=v1.x; xs[row][k0+ 5]=v1.y; xs[row][k0+ 6]=v1.z; xs[row][k0+ 7]=v1.w;
            xs[row][k0+ 8]=v2.x; xs[row][k0+ 9]=v2.y; xs[row][k0+10]=v2.z; xs[row][k0+11]=v2.w;
            xs[row][k0+12]=v3.x; xs[row][k0+13]=v3.y; xs[row][k0+14]=v3.z; xs[row][k0+15]=v3.w;
        }
        {   // stage W tile [64][128]
            int k = t >> 2, c0 = (t & 3) * 32;
            const float4* src = (const float4*)(W + (size_t)(kt + k) * DF + c0);
#pragma unroll
            for (int j = 0; j < 8; ++j)
                *(float4*)&ws[k][c0 + j * 4] = src[j];
        }
        __syncthreads();
#pragma unroll 4
        for (int k = 0; k < 64; ++k) {
            float xv[4];
#pragma unroll
            for (int ri = 0; ri < 4; ++ri) xv[ri] = xs[ty * 4 + ri][k];
            float4 w0 = *(float4*)&ws[k][tx * 8];
            float4 w1 = *(float4*)&ws[k][tx * 8 + 4];
#pragma unroll
            for (int ri = 0; ri < 4; ++ri) {
                acc[ri][0] += xv[ri] * w0.x; acc[ri][1] += xv[ri] * w0.y;
                acc[ri][2] += xv[ri] * w0.z; acc[ri][3] += xv[ri] * w0.w;
                acc[ri][4] += xv[ri] * w1.x; acc[ri][5] += xv[ri] * w1.y;
                acc[ri][6] += xv[ri] * w1.z; acc[ri][7] += xv[ri] * w1.w;
            }
        }
        __syncthreads();
    }
    // hbT (transposed bf16) for the PV MFMA
#pragma unroll
    for (int ci = 0; ci < 8; ++ci) {
        int col = tx * 8 + ci;
        ushort4 u;
        u.x = f2bf(acc[0][ci]); u.y = f2bf(acc[1][ci]);
        u.z = f2bf(acc[2][ci]); u.w = f2bf(acc[3][ci]);
        *(ushort4*)(hbT + (size_t)col * NR + rowbase + ty * 4) = u;
    }
    // s1 = h@a1, s2 = h@a2 fused: reduce across the 16-lane tx group
    float4 a1lo = *(const float4*)(a1 + tx * 8), a1hi = *(const float4*)(a1 + tx * 8 + 4);
    float4 a2lo = *(const float4*)(a2 + tx * 8), a2hi = *(const float4*)(a2 + tx * 8 + 4);
#pragma unroll
    for (int ri = 0; ri < 4; ++ri) {
        float p1 = acc[ri][0]*a1lo.x + acc[ri][1]*a1lo.y + acc[ri][2]*a1lo.z + acc[ri][3]*a1lo.w
                 + acc[ri][4]*a1hi.x + acc[ri][5]*a1hi.y + acc[ri][6]*a1hi.z + acc[ri][7]*a1hi.w;
        float p2 = acc[ri][0]*a2lo.x + acc[ri][1]*a2lo.y + acc[ri][2]*a2lo.z + acc[ri][3]*a2lo.w
                 + acc[ri][4]*a2hi.x + acc[ri][5]*a2hi.y + acc[ri][6]*a2hi.z + acc[ri][7]*a2hi.w;
#pragma unroll
        for (int off = 8; off > 0; off >>= 1) {
            p1 += __shfl_xor(p1, off);
            p2 += __shfl_xor(p2, off);
        }
        if (tx == 0) {
            s1[rowbase + ty * 4 + ri] = p1;
            s2[rowbase + ty * 4 + ri] = p2;
        }
    }
}

// ---------- Kernel B: flash over adj. No LDS staging, no barriers, no online max.
// grid (192 row-blocks, CH chunks) x 256 thr (4 waves x 16 rows). K-step 64.
__global__ __launch_bounds__(256, 3) void k_flash(
    const int* __restrict__ adj, const unsigned short* __restrict__ hbT,
    const float* __restrict__ s1, const float* __restrict__ s2,
    float* __restrict__ num, float* __restrict__ lC, int CW)
{
    const int t    = threadIdx.x;
    const int wid  = t >> 6, lane = t & 63;
    const int r    = lane & 15, g = lane >> 4;
    const int rowb = blockIdx.x * 64;
    const int prow = rowb + wid * 16 + r;
    const int chunk = blockIdx.y;
    const int j0 = chunk * CW;

    // prologue: global max of s1 (upper bound for all logits, per-row via s2)
    __shared__ float gred[4];
    float gm = NEGBIG;
    const float4* s14 = (const float4*)s1;
    for (int i = t; i < NR / 4; i += 256) {
        float4 v = s14[i];
        gm = fmaxf(fmaxf(v.x, v.y), fmaxf(fmaxf(v.z, v.w), gm));
    }
#pragma unroll
    for (int off = 32; off > 0; off >>= 1) gm = fmaxf(gm, __shfl_xor(gm, off));
    if (lane == 0) gred[wid] = gm;
    __syncthreads();
    gm = fmaxf(fmaxf(gred[0], gred[1]), fmaxf(gred[2], gred[3]));

    const float s2r = s2[prow];
    const float zub = s2r + gm;
    const float Mi  = fmaxf(zub, 0.2f * zub);   // lrelu(upper bound) >= every row logit

    float lsum = 0.f;
    f32x4 acc[8];
#pragma unroll
    for (int f = 0; f < 8; ++f) acc[f] = f32x4{0.f, 0.f, 0.f, 0.f};

    const int*   ap = adj + (size_t)prow * NR + j0 + g * 8;
    const float* sp = s1 + j0 + g * 8;
    const unsigned short* hp = hbT + (size_t)r * NR + j0 + g * 8;

    const int nsteps = CW >> 6;
    for (int it = 0; it < nsteps; ++it) {
        const int4   aa0 = *(const int4*)(ap);
        const int4   aa1 = *(const int4*)(ap + 4);
        const int4   ab0 = *(const int4*)(ap + 32);
        const int4   ab1 = *(const int4*)(ap + 36);
        const float4 sa0 = *(const float4*)(sp);
        const float4 sa1 = *(const float4*)(sp + 4);
        const float4 sb0 = *(const float4*)(sp + 32);
        const float4 sb1 = *(const float4*)(sp + 36);
        ap += 64; sp += 64;

        bf16x8 pf0, pf1;
#define PROC(mm, ss, dst, idx) { \
            float t0 = (ss) + s2r; \
            float lr = fmaxf(t0, 0.2f * t0); \
            float e  = ((mm) > 0) ? lr : NEGBIG; \
            float p  = __expf(e - Mi); \
            lsum += p; \
            dst[idx] = (__bf16)p; }
        PROC(aa0.x, sa0.x, pf0, 0) PROC(aa0.y, sa0.y, pf0, 1)
        PROC(aa0.z, sa0.z, pf0, 2) PROC(aa0.w, sa0.w, pf0, 3)
        PROC(aa1.x, sa1.x, pf0, 4) PROC(aa1.y, sa1.y, pf0, 5)
        PROC(aa1.z, sa1.z, pf0, 6) PROC(aa1.w, sa1.w, pf0, 7)
        PROC(ab0.x, sb0.x, pf1, 0) PROC(ab0.y, sb0.y, pf1, 1)
        PROC(ab0.z, sb0.z, pf1, 2) PROC(ab0.w, sb0.w, pf1, 3)
        PROC(ab1.x, sb1.x, pf1, 4) PROC(ab1.y, sb1.y, pf1, 5)
        PROC(ab1.z, sb1.z, pf1, 6) PROC(ab1.w, sb1.w, pf1, 7)
#undef PROC

#pragma unroll
        for (int f = 0; f < 8; ++f) {
            const unsigned short* rowp = hp + (size_t)f * (16 * NR) + (size_t)it * 64;
            bf16x8 b0 = *(const bf16x8*)(rowp);
            bf16x8 b1 = *(const bf16x8*)(rowp + 32);
            acc[f] = __builtin_amdgcn_mfma_f32_16x16x32_bf16(pf0, b0, acc[f], 0, 0, 0);
            acc[f] = __builtin_amdgcn_mfma_f32_16x16x32_bf16(pf1, b1, acc[f], 0, 0, 0);
        }
    }

    lsum += __shfl_xor(lsum, 16);
    lsum += __shfl_xor(lsum, 32);
    if (g == 0) lC[(size_t)chunk * NR + prow] = lsum;

    float* nb = num + (size_t)chunk * NR * DF;
#pragma unroll
    for (int f = 0; f < 8; ++f)
#pragma unroll
        for (int q = 0; q < 4; ++q) {
            int row = rowb + wid * 16 + g * 4 + q;   // C/D layout: row=(lane>>4)*4+reg
            nb[(size_t)row * DF + f * 16 + r] = acc[f][q];
        }
}

// ---------- Kernel C: combine chunk partials (shared M_i -> plain sums) ------
__global__ __launch_bounds__(256) void k_comb(
    const float* __restrict__ num, const float* __restrict__ lC,
    float* __restrict__ out, int CH)
{
    const int t   = threadIdx.x;
    const int row = blockIdx.x * 2 + (t >> 7);
    const int f   = t & 127;
    float L = 0.f, o = 0.f;
    for (int c = 0; c < CH; ++c) {
        L += lC[(size_t)c * NR + row];
        o += num[(size_t)c * NR * DF + (size_t)row * DF + f];
    }
    out[(size_t)row * DF + f] = o / L;
}

extern "C" void kernel_launch(void* const* d_in, const int* in_sizes, int n_in,
                              void* d_out, int out_size, void* d_ws, size_t ws_size,
                              hipStream_t stream)
{
    const float* x   = (const float*)d_in[0];
    const int*   adj = (const int*)d_in[1];
    const float* W   = (const float*)d_in[2];
    const float* a1  = (const float*)d_in[3];
    const float* a2  = (const float*)d_in[4];
    float* out = (float*)d_out;

    char* p = (char*)d_ws;
    unsigned short* hbT = (unsigned short*)p; p += (size_t)DF * NR * 2;
    float*          s1  = (float*)p;          p += (size_t)NR * 4;
    float*          s2  = (float*)p;          p += (size_t)NR * 4;
    size_t base = (size_t)(p - (char*)d_ws);
    size_t per  = (size_t)NR * DF * 4 + (size_t)NR * 4;
    int CH = 4;
    while (CH > 1 && base + (size_t)CH * per > ws_size) CH >>= 1;
    float* numb = (float*)p; p += (size_t)CH * NR * DF * 4;
    float* lC   = (float*)p;

    k_gemm_h<<<NR / 64, 256, 0, stream>>>(x, W, a1, a2, hbT, s1, s2);
    k_flash<<<dim3(NR / 64, CH), 256, 0, stream>>>(adj, hbT, s1, s2, numb, lC, NR / CH);
    k_comb<<<NR / 2, 256, 0, stream>>>(numb, lC, out, CH);
}

// Round 3
// 254.377 us; speedup vs baseline: 1.5975x; 1.5975x over previous
//
#include <hip/hip_runtime.h>
#include <hip/hip_bf16.h>

constexpr int NR = 12288;   // nodes
constexpr int KF = 256;     // in features
constexpr int DF = 128;     // out features
#define NEGBIG (-1e30f)

typedef __attribute__((ext_vector_type(8))) __bf16 bf16x8;
typedef __attribute__((ext_vector_type(4))) float  f32x4;

__device__ __forceinline__ unsigned short f2bf(float f) {
    union { float f; unsigned u; } v; v.f = f;
    unsigned r = v.u + 0x7FFFu + ((v.u >> 16) & 1u);
    return (unsigned short)(r >> 16);
}

// ---------- Kernel A: h = x@W (fp32 regs), emit hbT (bf16, transposed) + s1/s2
__global__ __launch_bounds__(256) void k_gemm_h(
    const float* __restrict__ x, const float* __restrict__ W,
    const float* __restrict__ a1, const float* __restrict__ a2,
    unsigned short* __restrict__ hbT, float* __restrict__ s1, float* __restrict__ s2)
{
    __shared__ __align__(16) float xs[64][65];
    __shared__ __align__(16) float ws[64][132];
    const int t  = threadIdx.x;
    const int tx = t & 15, ty = t >> 4;
    const int rowbase = blockIdx.x * 64;

    float acc[4][8];
#pragma unroll
    for (int i = 0; i < 4; ++i)
#pragma unroll
        for (int j = 0; j < 8; ++j) acc[i][j] = 0.f;

    for (int kt = 0; kt < KF; kt += 64) {
        {   // stage x tile [64][64]
            int row = t >> 2, k0 = (t & 3) * 16;
            const float4* src = (const float4*)(x + (size_t)(rowbase + row) * KF + kt + k0);
            float4 v0 = src[0], v1 = src[1], v2 = src[2], v3 = src[3];
            xs[row][k0+ 0]=v0.x; xs[row][k0+ 1]=v0.y; xs[row][k0+ 2]=v0.z; xs[row][k0+ 3]=v0.w;
            xs[row][k0+ 4]=v1.x; xs[row][k0+ 5]=v1.y; xs[row][k0+ 6]=v1.z; xs[row][k0+ 7]=v1.w;
            xs[row][k0+ 8]=v2.x; xs[row][k0+ 9]=v2.y; xs[row][k0+10]=v2.z; xs[row][k0+11]=v2.w;
            xs[row][k0+12]=v3.x; xs[row][k0+13]=v3.y; xs[row][k0+14]=v3.z; xs[row][k0+15]=v3.w;
        }
        {   // stage W tile [64][128]
            int k = t >> 2, c0 = (t & 3) * 32;
            const float4* src = (const float4*)(W + (size_t)(kt + k) * DF + c0);
#pragma unroll
            for (int j = 0; j < 8; ++j)
                *(float4*)&ws[k][c0 + j * 4] = src[j];
        }
        __syncthreads();
#pragma unroll 4
        for (int k = 0; k < 64; ++k) {
            float xv[4];
#pragma unroll
            for (int ri = 0; ri < 4; ++ri) xv[ri] = xs[ty * 4 + ri][k];
            float4 w0 = *(float4*)&ws[k][tx * 8];
            float4 w1 = *(float4*)&ws[k][tx * 8 + 4];
#pragma unroll
            for (int ri = 0; ri < 4; ++ri) {
                acc[ri][0] += xv[ri] * w0.x; acc[ri][1] += xv[ri] * w0.y;
                acc[ri][2] += xv[ri] * w0.z; acc[ri][3] += xv[ri] * w0.w;
                acc[ri][4] += xv[ri] * w1.x; acc[ri][5] += xv[ri] * w1.y;
                acc[ri][6] += xv[ri] * w1.z; acc[ri][7] += xv[ri] * w1.w;
            }
        }
        __syncthreads();
    }
    // hbT (transposed bf16) for the PV MFMA
#pragma unroll
    for (int ci = 0; ci < 8; ++ci) {
        int col = tx * 8 + ci;
        ushort4 u;
        u.x = f2bf(acc[0][ci]); u.y = f2bf(acc[1][ci]);
        u.z = f2bf(acc[2][ci]); u.w = f2bf(acc[3][ci]);
        *(ushort4*)(hbT + (size_t)col * NR + rowbase + ty * 4) = u;
    }
    // s1 = h@a1, s2 = h@a2 fused
    float4 a1lo = *(const float4*)(a1 + tx * 8), a1hi = *(const float4*)(a1 + tx * 8 + 4);
    float4 a2lo = *(const float4*)(a2 + tx * 8), a2hi = *(const float4*)(a2 + tx * 8 + 4);
#pragma unroll
    for (int ri = 0; ri < 4; ++ri) {
        float p1 = acc[ri][0]*a1lo.x + acc[ri][1]*a1lo.y + acc[ri][2]*a1lo.z + acc[ri][3]*a1lo.w
                 + acc[ri][4]*a1hi.x + acc[ri][5]*a1hi.y + acc[ri][6]*a1hi.z + acc[ri][7]*a1hi.w;
        float p2 = acc[ri][0]*a2lo.x + acc[ri][1]*a2lo.y + acc[ri][2]*a2lo.z + acc[ri][3]*a2lo.w
                 + acc[ri][4]*a2hi.x + acc[ri][5]*a2hi.y + acc[ri][6]*a2hi.z + acc[ri][7]*a2hi.w;
#pragma unroll
        for (int off = 8; off > 0; off >>= 1) {
            p1 += __shfl_xor(p1, off);
            p2 += __shfl_xor(p2, off);
        }
        if (tx == 0) {
            s1[rowbase + ty * 4 + ri] = p1;
            s2[rowbase + ty * 4 + ri] = p2;
        }
    }
}

// ---------- Kernel A2: global max of s1 (one block) --------------------------
__global__ __launch_bounds__(1024) void k_gmax(
    const float* __restrict__ s1, float* __restrict__ gmax)
{
    __shared__ float red[16];
    const int t = threadIdx.x;
    float m = NEGBIG;
    const float4* s4 = (const float4*)s1;
    for (int i = t; i < NR / 4; i += 1024) {
        float4 v = s4[i];
        m = fmaxf(fmaxf(v.x, v.y), fmaxf(fmaxf(v.z, v.w), m));
    }
#pragma unroll
    for (int off = 32; off > 0; off >>= 1) m = fmaxf(m, __shfl_xor(m, off));
    if ((t & 63) == 0) red[t >> 6] = m;
    __syncthreads();
    if (t < 16) {
        m = red[t];
#pragma unroll
        for (int off = 8; off > 0; off >>= 1) m = fmaxf(m, __shfl_xor(m, off));
        if (t == 0) gmax[0] = m;
    }
}

// ---------- Kernel B: flash over adj. LDS dbuf + depth-1 prefetch, 1 barrier/iter.
// grid (192 row-blocks, CH chunks) x 256 thr (4 waves x 16 rows). K-step 32.
__global__ __launch_bounds__(256, 5) void k_flash(
    const int* __restrict__ adj, const unsigned short* __restrict__ hbT,
    const float* __restrict__ s1, const float* __restrict__ s2,
    const float* __restrict__ gmaxp,
    float* __restrict__ num, float* __restrict__ lC, int CW)
{
    __shared__ __align__(16) unsigned short hbuf[2][128][40]; // pad 32->40: 2-way max (free)
    const int t    = threadIdx.x;
    const int wid  = t >> 6, lane = t & 63;
    const int r    = lane & 15, g = lane >> 4;
    const int rowb = blockIdx.x * 64;
    const int prow = rowb + wid * 16 + r;
    const int chunk = blockIdx.y;
    const int j0 = chunk * CW;

    const float gm  = gmaxp[0];
    const float s2r = s2[prow];
    const float zub = s2r + gm;
    const float Mi  = fmaxf(zub, 0.2f * zub);   // lrelu(ub) >= every logit in this row

    float lsum = 0.f;
    f32x4 acc[8];
#pragma unroll
    for (int f = 0; f < 8; ++f) acc[f] = f32x4{0.f, 0.f, 0.f, 0.f};

    const int*   ab = adj + (size_t)prow * NR + j0 + g * 8;
    const float* sb = s1 + j0 + g * 8;
    const int sr = t >> 1, scol = (t & 1) * 16;
    const unsigned short* hs = hbT + (size_t)sr * NR + j0 + scol;

    const int nsteps = CW >> 5;

    // prologue: stage iter-0 tile
    {
        int4   Aa0 = *(const int4*)(ab);        // prefetched below into Aa/Ab path
        int4   Ab0 = *(const int4*)(ab + 4);
        bf16x8 Ta  = *(const bf16x8*)(hs);
        bf16x8 Tb  = *(const bf16x8*)(hs + 8);
        *(bf16x8*)&hbuf[0][sr][scol]     = Ta;
        *(bf16x8*)&hbuf[0][sr][scol + 8] = Tb;
        // keep adj regs live into loop
        __syncthreads();
        int cur = 0;
        int4 Aa = Aa0, Ab = Ab0;
        for (int it = 0; it < nsteps; ++it) {
            const int itn = (it + 1 < nsteps) ? (it + 1) : 0;
            // prefetch next iteration (HBM adj + L2 hbT) into registers
            int4   NAa = *(const int4*)(ab + itn * 32);
            int4   NAb = *(const int4*)(ab + itn * 32 + 4);
            bf16x8 NTa = *(const bf16x8*)(hs + itn * 32);
            bf16x8 NTb = *(const bf16x8*)(hs + itn * 32 + 8);
            // current s1 slice (tiny, cache-hot)
            const float4 Sa = *(const float4*)(sb + it * 32);
            const float4 Sb = *(const float4*)(sb + it * 32 + 4);

            bf16x8 pf;
#define PROC(mm, ss, idx) { \
                float t0 = (ss) + s2r; \
                float lr = fmaxf(t0, 0.2f * t0); \
                float e  = ((mm) > 0) ? lr : NEGBIG; \
                float p  = __expf(e - Mi); \
                lsum += p; \
                pf[idx] = (__bf16)p; }
            PROC(Aa.x, Sa.x, 0) PROC(Aa.y, Sa.y, 1)
            PROC(Aa.z, Sa.z, 2) PROC(Aa.w, Sa.w, 3)
            PROC(Ab.x, Sb.x, 4) PROC(Ab.y, Sb.y, 5)
            PROC(Ab.z, Sb.z, 6) PROC(Ab.w, Sb.w, 7)
#undef PROC

#pragma unroll
            for (int f = 0; f < 8; ++f) {
                bf16x8 bfr = *(const bf16x8*)&hbuf[cur][f * 16 + r][g * 8];
                acc[f] = __builtin_amdgcn_mfma_f32_16x16x32_bf16(pf, bfr, acc[f], 0, 0, 0);
            }

            // stage next tile (vmcnt wait lands here, after compute)
            *(bf16x8*)&hbuf[cur ^ 1][sr][scol]     = NTa;
            *(bf16x8*)&hbuf[cur ^ 1][sr][scol + 8] = NTb;
            __syncthreads();
            Aa = NAa; Ab = NAb; cur ^= 1;
        }
    }

    lsum += __shfl_xor(lsum, 16);
    lsum += __shfl_xor(lsum, 32);
    if (g == 0) lC[(size_t)chunk * NR + prow] = lsum;

    float* nb = num + (size_t)chunk * NR * DF;
#pragma unroll
    for (int f = 0; f < 8; ++f)
#pragma unroll
        for (int q = 0; q < 4; ++q) {
            int row = rowb + wid * 16 + g * 4 + q;   // C/D layout: row=(lane>>4)*4+reg
            nb[(size_t)row * DF + f * 16 + r] = acc[f][q];
        }
}

// ---------- Kernel C: combine chunk partials (shared M_i -> plain sums) ------
__global__ __launch_bounds__(256) void k_comb(
    const float* __restrict__ num, const float* __restrict__ lC,
    float* __restrict__ out, int CH)
{
    const int t   = threadIdx.x;
    const int row = blockIdx.x * 2 + (t >> 7);
    const int f   = t & 127;
    float L = 0.f, o = 0.f;
    for (int c = 0; c < CH; ++c) {
        L += lC[(size_t)c * NR + row];
        o += num[(size_t)c * NR * DF + (size_t)row * DF + f];
    }
    out[(size_t)row * DF + f] = o / L;
}

extern "C" void kernel_launch(void* const* d_in, const int* in_sizes, int n_in,
                              void* d_out, int out_size, void* d_ws, size_t ws_size,
                              hipStream_t stream)
{
    const float* x   = (const float*)d_in[0];
    const int*   adj = (const int*)d_in[1];
    const float* W   = (const float*)d_in[2];
    const float* a1  = (const float*)d_in[3];
    const float* a2  = (const float*)d_in[4];
    float* out = (float*)d_out;

    char* p = (char*)d_ws;
    unsigned short* hbT = (unsigned short*)p; p += (size_t)DF * NR * 2;
    float*          s1  = (float*)p;          p += (size_t)NR * 4;
    float*          s2  = (float*)p;          p += (size_t)NR * 4;
    float*          gmx = (float*)p;          p += 256;
    size_t base = (size_t)(p - (char*)d_ws);
    size_t per  = (size_t)NR * DF * 4 + (size_t)NR * 4;
    int CH = 8;
    while (CH > 1 && base + (size_t)CH * per > ws_size) CH >>= 1;
    float* numb = (float*)p; p += (size_t)CH * NR * DF * 4;
    float* lC   = (float*)p;

    k_gemm_h<<<NR / 64, 256, 0, stream>>>(x, W, a1, a2, hbT, s1, s2);
    k_gmax<<<1, 1024, 0, stream>>>(s1, gmx);
    k_flash<<<dim3(NR / 64, CH), 256, 0, stream>>>(adj, hbT, s1, s2, gmx, numb, lC, NR / CH);
    k_comb<<<NR / 2, 256, 0, stream>>>(numb, lC, out, CH);
}